// Round 2
// baseline (443.292 us; speedup 1.0000x reference)
//
#include <hip/hip_runtime.h>
#include <hip/hip_bf16.h>
#include <stdint.h>

#define B_ 8
#define S_ 2048
#define E_ 768

typedef __attribute__((ext_vector_type(4))) float f32x4;
typedef __attribute__((ext_vector_type(8))) short bf16x8;

__device__ __forceinline__ unsigned short f2bf(float f) {
  union { float f; unsigned u; } v; v.f = f;
  unsigned r = v.u + 0x7FFFu + ((v.u >> 16) & 1u);
  return (unsigned short)(r >> 16);
}

// Stage a 128x32 bf16 tile (8192 B) from global (row stride ld elements) into LDS
// via global_load_lds dwordx4. 4 waves x 2 chunks x 64 lanes x 16 B = 8192 B.
__device__ __forceinline__ void stage_bf16(const unsigned short* __restrict__ gsrc, int ld,
                                           unsigned short* lds, int wid, int lane) {
#pragma unroll
  for (int ii = 0; ii < 2; ++ii) {
    const unsigned lin = (unsigned)(wid * 2 + ii) * 1024u + (unsigned)lane * 16u;
    const unsigned row = lin >> 6;   // 64 B per LDS row (32 bf16)
    const unsigned cb = lin & 63u;
    const char* g = (const char*)gsrc + (size_t)row * (size_t)ld * 2 + cb;
    __builtin_amdgcn_global_load_lds((const __attribute__((address_space(1))) void*)g,
                                     (__attribute__((address_space(3))) void*)((char*)lds + lin),
                                     16, 0, 0);
  }
}

// ---------------- K0: pack mask int32 -> bitmask (bit=1 means masked out) -----------
__global__ __launch_bounds__(256) void k_maskpack(const int* __restrict__ mask,
                                                  unsigned long long* __restrict__ mbits) {
  const int nwords = B_ * S_ * (S_ / 64);  // 524288
  const int wave = (blockIdx.x * 256 + threadIdx.x) >> 6;
  const int lane = threadIdx.x & 63;
  const int nwaves = gridDim.x * 4;
#pragma unroll 4
  for (int w = wave; w < nwords; w += nwaves) {
    int mk = mask[(size_t)w * 64 + lane];
    unsigned long long bal = __ballot(mk == 1);
    if (lane == 0) mbits[w] = bal;
  }
}

// ---------------- K1: projection GEMM  O = X @ W^T + b  (f32 in, bf16 out) -----------
__global__ __launch_bounds__(256) void k_proj(const float* __restrict__ qin,
                                              const float* __restrict__ kin,
                                              const float* __restrict__ vin,
                                              const float* __restrict__ W,
                                              const float* __restrict__ bias,
                                              unsigned short* __restrict__ qp,
                                              unsigned short* __restrict__ kp,
                                              unsigned short* __restrict__ vp) {
  __shared__ __attribute__((aligned(16))) unsigned short As[128 * 32];
  __shared__ __attribute__((aligned(16))) unsigned short Bs[128 * 32];
  const int tid = threadIdx.x;
  const int lane = tid & 63;
  const int wid = tid >> 6;
  const int wr = (wid >> 1) * 64;
  const int wc = (wid & 1) * 64;
  const int r0 = blockIdx.x * 128;
  const int c0 = blockIdx.y * 128;
  const int z = blockIdx.z;
  const float* X = (z == 0) ? qin : ((z == 1) ? kin : vin);
  unsigned short* O = (z == 0) ? qp : ((z == 1) ? kp : vp);

  const int srow = tid >> 3;       // 0..31 within 128 via i*32
  const int sc4 = tid & 7;

  f32x4 acc[4][4] = {};
  float4 fa[4], fw[4];

#pragma unroll
  for (int i = 0; i < 4; ++i) {
    int row = i * 32 + srow;
    fa[i] = *reinterpret_cast<const float4*>(&X[(size_t)(r0 + row) * E_ + sc4 * 4]);
    fw[i] = *reinterpret_cast<const float4*>(&W[(size_t)(c0 + row) * E_ + sc4 * 4]);
  }

  for (int k0i = 0; k0i < 24; ++k0i) {
    const int k0n = (k0i + 1) * 32;
#pragma unroll
    for (int i = 0; i < 4; ++i) {
      int row = i * 32 + srow;
      uint2 pa, pw;
      pa.x = (unsigned)f2bf(fa[i].x) | ((unsigned)f2bf(fa[i].y) << 16);
      pa.y = (unsigned)f2bf(fa[i].z) | ((unsigned)f2bf(fa[i].w) << 16);
      pw.x = (unsigned)f2bf(fw[i].x) | ((unsigned)f2bf(fw[i].y) << 16);
      pw.y = (unsigned)f2bf(fw[i].z) | ((unsigned)f2bf(fw[i].w) << 16);
      *reinterpret_cast<uint2*>(&As[row * 32 + sc4 * 4]) = pa;
      *reinterpret_cast<uint2*>(&Bs[row * 32 + sc4 * 4]) = pw;
    }
    __syncthreads();
    if (k0i < 23) {
#pragma unroll
      for (int i = 0; i < 4; ++i) {
        int row = i * 32 + srow;
        fa[i] = *reinterpret_cast<const float4*>(&X[(size_t)(r0 + row) * E_ + k0n + sc4 * 4]);
        fw[i] = *reinterpret_cast<const float4*>(&W[(size_t)(c0 + row) * E_ + k0n + sc4 * 4]);
      }
    }
    bf16x8 af[4], bfr[4];
#pragma unroll
    for (int m = 0; m < 4; ++m)
      af[m] = *reinterpret_cast<const bf16x8*>(&As[(wr + m * 16 + (lane & 15)) * 32 + (lane >> 4) * 8]);
#pragma unroll
    for (int n = 0; n < 4; ++n)
      bfr[n] = *reinterpret_cast<const bf16x8*>(&Bs[(wc + n * 16 + (lane & 15)) * 32 + (lane >> 4) * 8]);
#pragma unroll
    for (int m = 0; m < 4; ++m)
#pragma unroll
      for (int n = 0; n < 4; ++n)
        acc[m][n] = __builtin_amdgcn_mfma_f32_16x16x32_bf16(af[m], bfr[n], acc[m][n], 0, 0, 0);
    __syncthreads();
  }

#pragma unroll
  for (int n = 0; n < 4; ++n) {
    int gc = c0 + wc + n * 16 + (lane & 15);
    float bv = bias[gc];
#pragma unroll
    for (int m = 0; m < 4; ++m) {
      int gr = r0 + wr + m * 16 + (lane >> 4) * 4;
#pragma unroll
      for (int r = 0; r < 4; ++r) {
        O[(size_t)(gr + r) * E_ + gc] = f2bf(acc[m][n][r] + bv);
      }
    }
  }
}

// ---------------- K1b: transpose vp [B*S][E] -> vpT [B][E][S] ------------------------
__global__ __launch_bounds__(256) void k_vtrans(const unsigned short* __restrict__ vp,
                                                unsigned short* __restrict__ vpT) {
  __shared__ __attribute__((aligned(16))) unsigned short t[64][72];
  const int tid = threadIdx.x;
  const int st = blockIdx.x;  // s tile: 2048/64 = 32
  const int ot = blockIdx.y;  // o tile: 768/64 = 12
  const int b = blockIdx.z;
#pragma unroll
  for (int i = 0; i < 2; ++i) {
    int f = i * 256 + tid;  // 16B-unit index, 512 total
    int s = f >> 3, c8 = f & 7;
    uint4 vv = *reinterpret_cast<const uint4*>(
        &vp[((size_t)b * S_ + st * 64 + s) * E_ + ot * 64 + c8 * 8]);
    *reinterpret_cast<uint4*>(&t[s][c8 * 8]) = vv;
  }
  __syncthreads();
  const int o = tid >> 2;
  const int sb = (tid & 3) * 16;
  unsigned p[8];
#pragma unroll
  for (int j = 0; j < 8; ++j)
    p[j] = (unsigned)t[sb + 2 * j][o] | ((unsigned)t[sb + 2 * j + 1][o] << 16);
  uint4 w0 = make_uint4(p[0], p[1], p[2], p[3]);
  uint4 w1 = make_uint4(p[4], p[5], p[6], p[7]);
  size_t ob = ((size_t)b * E_ + ot * 64 + o) * S_ + st * 64 + sb;
  *reinterpret_cast<uint4*>(&vpT[ob]) = w0;
  *reinterpret_cast<uint4*>(&vpT[ob + 8]) = w1;
}

// ---------------- K2: scores = qp @ kp^T, mask, exp (unnormalized), rowsum ----------
__global__ __launch_bounds__(256) void k_scores(const unsigned short* __restrict__ qp,
                                                const unsigned short* __restrict__ kp,
                                                const unsigned* __restrict__ mbits,
                                                unsigned short* __restrict__ P,
                                                float* __restrict__ rowsum) {
  __shared__ __attribute__((aligned(16))) unsigned short As[2][128 * 32];
  __shared__ __attribute__((aligned(16))) unsigned short Bs[2][128 * 32];
  __shared__ float rlds[128][2];
  const int tid = threadIdx.x, lane = tid & 63, wid = tid >> 6;
  const int wr = (wid >> 1) * 64, wc = (wid & 1) * 64;
  const int qt = blockIdx.x, g = blockIdx.y, b = blockIdx.z;
  const unsigned short* Abase = qp + ((size_t)b * S_ + qt * 128) * E_;
  const float SC = (float)(1.4426950408889634 / 27.712812921102035);  // log2(e)/sqrt(768)
  float rs[4][4] = {{0.f}};

  for (int nt = 0; nt < 2; ++nt) {
    const int kv0 = g * 256 + nt * 128;
    const unsigned short* Bbase = kp + ((size_t)b * S_ + kv0) * E_;
    f32x4 acc[4][4] = {};

    stage_bf16(Abase, E_, As[0], wid, lane);
    stage_bf16(Bbase, E_, Bs[0], wid, lane);
    __syncthreads();
    int cur = 0;
#pragma unroll 2
    for (int t = 0; t < 24; ++t) {
      if (t < 23) {
        stage_bf16(Abase + (t + 1) * 32, E_, As[cur ^ 1], wid, lane);
        stage_bf16(Bbase + (t + 1) * 32, E_, Bs[cur ^ 1], wid, lane);
      }
      bf16x8 af[4], bfr[4];
#pragma unroll
      for (int m = 0; m < 4; ++m)
        af[m] = *reinterpret_cast<const bf16x8*>(&As[cur][(wr + m * 16 + (lane & 15)) * 32 + (lane >> 4) * 8]);
#pragma unroll
      for (int n = 0; n < 4; ++n)
        bfr[n] = *reinterpret_cast<const bf16x8*>(&Bs[cur][(wc + n * 16 + (lane & 15)) * 32 + (lane >> 4) * 8]);
#pragma unroll
      for (int m = 0; m < 4; ++m)
#pragma unroll
        for (int n = 0; n < 4; ++n)
          acc[m][n] = __builtin_amdgcn_mfma_f32_16x16x32_bf16(af[m], bfr[n], acc[m][n], 0, 0, 0);
      __syncthreads();
      cur ^= 1;
    }

#pragma unroll
    for (int m = 0; m < 4; ++m) {
#pragma unroll
      for (int r = 0; r < 4; ++r) {
        const int grow = qt * 128 + wr + m * 16 + (lane >> 4) * 4 + r;
        const size_t rowoff = ((size_t)b * S_ + grow) * S_;
        const uint2 mb = *reinterpret_cast<const uint2*>(
            &mbits[((size_t)b * S_ + grow) * 64 + ((kv0 + wc) >> 5)]);
        float radd = 0.f;
#pragma unroll
        for (int n = 0; n < 4; ++n) {
          const int gcol = kv0 + wc + n * 16 + (lane & 15);
          const unsigned wsel = (n & 2) ? mb.y : mb.x;
          const int sh = (lane & 15) + ((n & 1) << 4);
          float pv = ((wsel >> sh) & 1u) ? 0.f : __builtin_amdgcn_exp2f(acc[m][n][r] * SC);
          radd += pv;
          P[rowoff + gcol] = f2bf(pv);
        }
        rs[m][r] += radd;
      }
    }
  }

#pragma unroll
  for (int m = 0; m < 4; ++m)
#pragma unroll
    for (int r = 0; r < 4; ++r) {
      float vsum = rs[m][r];
      vsum += __shfl_xor(vsum, 1);
      vsum += __shfl_xor(vsum, 2);
      vsum += __shfl_xor(vsum, 4);
      vsum += __shfl_xor(vsum, 8);
      if ((lane & 15) == 0) rlds[wr + m * 16 + (lane >> 4) * 4 + r][wid & 1] = vsum;
    }
  __syncthreads();
  if (tid < 128) {
    float tot = rlds[tid][0] + rlds[tid][1];
    rowsum[(size_t)g * (B_ * S_) + (size_t)b * S_ + qt * 128 + tid] = tot;
  }
}

// ---------------- K2b: inv_rs = 1 / sum_g rowsum ------------------------------------
__global__ __launch_bounds__(256) void k_invrs(const float* __restrict__ rowsum,
                                               float* __restrict__ inv_rs) {
  int i = blockIdx.x * 256 + threadIdx.x;
  float t = 0.f;
#pragma unroll
  for (int g = 0; g < 8; ++g) t += rowsum[g * (B_ * S_) + i];
  inv_rs[i] = 1.0f / t;
}

// ---------------- K3: out = (P @ vpT^T) * inv_rs  (f32 out) -------------------------
__global__ __launch_bounds__(256) void k_pv(const unsigned short* __restrict__ P,
                                            const unsigned short* __restrict__ vpT,
                                            const float* __restrict__ inv_rs,
                                            float* __restrict__ out) {
  __shared__ __attribute__((aligned(16))) unsigned short As[2][128 * 32];
  __shared__ __attribute__((aligned(16))) unsigned short Bs[2][128 * 32];
  const int tid = threadIdx.x, lane = tid & 63, wid = tid >> 6;
  const int wr = (wid >> 1) * 64, wc = (wid & 1) * 64;
  const int mt = blockIdx.x, nt = blockIdx.y, b = blockIdx.z;
  const unsigned short* Abase = P + ((size_t)b * S_ + mt * 128) * S_;
  const unsigned short* Bbase = vpT + ((size_t)b * E_ + nt * 128) * S_;
  f32x4 acc[4][4] = {};

  stage_bf16(Abase, S_, As[0], wid, lane);
  stage_bf16(Bbase, S_, Bs[0], wid, lane);
  __syncthreads();
  int cur = 0;
#pragma unroll 2
  for (int t = 0; t < 64; ++t) {
    if (t < 63) {
      stage_bf16(Abase + (t + 1) * 32, S_, As[cur ^ 1], wid, lane);
      stage_bf16(Bbase + (t + 1) * 32, S_, Bs[cur ^ 1], wid, lane);
    }
    bf16x8 af[4], bfr[4];
#pragma unroll
    for (int m = 0; m < 4; ++m)
      af[m] = *reinterpret_cast<const bf16x8*>(&As[cur][(wr + m * 16 + (lane & 15)) * 32 + (lane >> 4) * 8]);
#pragma unroll
    for (int n = 0; n < 4; ++n)
      bfr[n] = *reinterpret_cast<const bf16x8*>(&Bs[cur][(wc + n * 16 + (lane & 15)) * 32 + (lane >> 4) * 8]);
#pragma unroll
    for (int m = 0; m < 4; ++m)
#pragma unroll
      for (int n = 0; n < 4; ++n)
        acc[m][n] = __builtin_amdgcn_mfma_f32_16x16x32_bf16(af[m], bfr[n], acc[m][n], 0, 0, 0);
    __syncthreads();
    cur ^= 1;
  }

#pragma unroll
  for (int m = 0; m < 4; ++m)
#pragma unroll
    for (int r = 0; r < 4; ++r) {
      const int grow = mt * 128 + wr + m * 16 + (lane >> 4) * 4 + r;
      const float inv = inv_rs[b * S_ + grow];
#pragma unroll
      for (int n = 0; n < 4; ++n) {
        const int gcol = nt * 128 + wc + n * 16 + (lane & 15);
        out[((size_t)b * S_ + grow) * E_ + gcol] = acc[m][n][r] * inv;
      }
    }
}

extern "C" void kernel_launch(void* const* d_in, const int* in_sizes, int n_in,
                              void* d_out, int out_size, void* d_ws, size_t ws_size,
                              hipStream_t stream) {
  const float* q = (const float*)d_in[0];
  const float* k = (const float*)d_in[1];
  const float* v = (const float*)d_in[2];
  const int* mask = (const int*)d_in[3];
  const float* W = (const float*)d_in[4];
  const float* bias = (const float*)d_in[5];
  float* out = (float*)d_out;
  char* ws = (char*)d_ws;

  // workspace layout (bytes)
  unsigned short* qp = (unsigned short*)(ws + 0);           //  24 MB
  unsigned short* kp = (unsigned short*)(ws + 25165824);    //  24 MB
  unsigned short* vpT = (unsigned short*)(ws + 50331648);   //  24 MB
  unsigned short* P = (unsigned short*)(ws + 75497472);     //  64 MiB
  unsigned short* vp_tmp = P;  // reused: consumed by k_vtrans before k_scores writes P
  float* rowsum = (float*)(ws + 142606336);                 // 8*B*S f32 = 512 KB
  float* inv_rs = (float*)(ws + 143130624);                 // B*S f32 = 64 KB
  unsigned long long* mbits = (unsigned long long*)(ws + 143196160);  // 4 MB
  (void)in_sizes; (void)n_in; (void)out_size; (void)ws_size;

  dim3 blk(256, 1, 1);
  k_maskpack<<<dim3(2048, 1, 1), blk, 0, stream>>>(mask, mbits);
  k_proj<<<dim3(128, 6, 3), blk, 0, stream>>>(q, k, v, W, bias, qp, kp, vp_tmp);
  k_vtrans<<<dim3(32, 12, 8), blk, 0, stream>>>(vp_tmp, vpT);
  k_scores<<<dim3(16, 8, 8), blk, 0, stream>>>(qp, kp, (const unsigned*)mbits, P, rowsum);
  k_invrs<<<dim3(64, 1, 1), blk, 0, stream>>>(rowsum, inv_rs);
  k_pv<<<dim3(16, 6, 8), blk, 0, stream>>>(P, vpT, inv_rs, out);
}

// Round 3
// 354.714 us; speedup vs baseline: 1.2497x; 1.2497x over previous
//
#include <hip/hip_runtime.h>
#include <hip/hip_bf16.h>
#include <stdint.h>

#define B_ 8
#define S_ 2048
#define E_ 768

typedef __attribute__((ext_vector_type(4))) float f32x4;
typedef __attribute__((ext_vector_type(8))) short bf16x8;

// Pipelined GEMM core geometry: BM=256, BN=128, BK=64, 512 thr (8 waves 4Mx2N)
#define A_TILE_USH (256 * 64)  // 32 KB
#define B_TILE_USH (128 * 64)  // 16 KB

__device__ __forceinline__ unsigned short f2bf(float f) {
  union { float f; unsigned u; } v; v.f = f;
  unsigned r = v.u + 0x7FFFu + ((v.u >> 16) & 1u);
  return (unsigned short)(r >> 16);
}

__device__ __forceinline__ void gll16(const void* g, void* l) {
  __builtin_amdgcn_global_load_lds((const __attribute__((address_space(1))) void*)g,
                                   (__attribute__((address_space(3))) void*)l, 16, 0, 0);
}

// Stage K-tile kt (A: 256x64 bf16, B: 128x64 bf16). 6 global_load_lds per thread.
// LDS dest is linear (required); global SOURCE is pre-swizzled with the same XOR
// the reader applies (involution): cb ^= (row&7)<<4  (rule #21 both-sides).
__device__ __forceinline__ void stage_tile(const char* Ab, const char* Bb,
                                           int ldAb, int ldBb, int kt,
                                           unsigned short* As, unsigned short* Bs, int tid) {
#pragma unroll
  for (int i = 0; i < 4; ++i) {
    const unsigned lin = (unsigned)i * 8192u + (unsigned)tid * 16u;
    const unsigned row = lin >> 7, cb = lin & 127u;
    const unsigned cbs = cb ^ ((row & 7u) << 4);
    gll16(Ab + (size_t)row * ldAb + (size_t)kt * 128 + cbs, (char*)As + lin);
  }
#pragma unroll
  for (int i = 0; i < 2; ++i) {
    const unsigned lin = (unsigned)i * 8192u + (unsigned)tid * 16u;
    const unsigned row = lin >> 7, cb = lin & 127u;
    const unsigned cbs = cb ^ ((row & 7u) << 4);
    gll16(Bb + (size_t)row * ldBb + (size_t)kt * 128 + cbs, (char*)Bs + lin);
  }
}

__device__ __forceinline__ void compute_tile(const unsigned short* As, const unsigned short* Bs,
                                             int wm, int wn, int lane, f32x4 (&acc)[4][4]) {
  bf16x8 af[4][2], bv[4][2];
#pragma unroll
  for (int m = 0; m < 4; ++m) {
    const int row = wm * 64 + m * 16 + (lane & 15);
#pragma unroll
    for (int ks = 0; ks < 2; ++ks) {
      const unsigned cb = ((unsigned)ks * 64u + (unsigned)(lane >> 4) * 16u) ^ (((unsigned)row & 7u) << 4);
      af[m][ks] = *reinterpret_cast<const bf16x8*>((const char*)As + row * 128 + cb);
    }
  }
#pragma unroll
  for (int n = 0; n < 4; ++n) {
    const int row = wn * 64 + n * 16 + (lane & 15);
#pragma unroll
    for (int ks = 0; ks < 2; ++ks) {
      const unsigned cb = ((unsigned)ks * 64u + (unsigned)(lane >> 4) * 16u) ^ (((unsigned)row & 7u) << 4);
      bv[n][ks] = *reinterpret_cast<const bf16x8*>((const char*)Bs + row * 128 + cb);
    }
  }
  __builtin_amdgcn_s_setprio(1);
#pragma unroll
  for (int ks = 0; ks < 2; ++ks)
#pragma unroll
    for (int m = 0; m < 4; ++m)
#pragma unroll
      for (int n = 0; n < 4; ++n)
        acc[m][n] = __builtin_amdgcn_mfma_f32_16x16x32_bf16(af[m][ks], bv[n][ks], acc[m][n], 0, 0, 0);
  __builtin_amdgcn_s_setprio(0);
}

// 3-stage pipeline: stage(kt+2) at iter top; one raw barrier per K-tile with
// counted vmcnt(6) (= loads/tile; tile kt+1 is the oldest 6 outstanding).
__device__ __forceinline__ void gemm_pipe(const char* Ab, const char* Bb, int ldAb, int ldBb,
                                          int NT, unsigned short* AsAll, unsigned short* BsAll,
                                          int tid, int wm, int wn, int lane, f32x4 (&acc)[4][4]) {
  stage_tile(Ab, Bb, ldAb, ldBb, 0, AsAll, BsAll, tid);
  stage_tile(Ab, Bb, ldAb, ldBb, 1, AsAll + A_TILE_USH, BsAll + B_TILE_USH, tid);
  asm volatile("s_waitcnt vmcnt(6)" ::: "memory");
  __builtin_amdgcn_s_barrier();
  __builtin_amdgcn_sched_barrier(0);
  for (int kt = 0; kt < NT; ++kt) {
    const int bk = kt % 3;
    if (kt + 2 < NT) {
      const int bs = (kt + 2) % 3;
      stage_tile(Ab, Bb, ldAb, ldBb, kt + 2, AsAll + bs * A_TILE_USH, BsAll + bs * B_TILE_USH, tid);
    }
    compute_tile(AsAll + bk * A_TILE_USH, BsAll + bk * B_TILE_USH, wm, wn, lane, acc);
    if (kt + 1 < NT) {
      if (kt + 2 < NT) asm volatile("s_waitcnt vmcnt(6) lgkmcnt(0)" ::: "memory");
      else             asm volatile("s_waitcnt vmcnt(0) lgkmcnt(0)" ::: "memory");
      __builtin_amdgcn_s_barrier();
      __builtin_amdgcn_sched_barrier(0);
    }
  }
}

// ---------------- K0: pack mask int32 -> bitmask (bit=1 means masked out) -----------
__global__ __launch_bounds__(256) void k_maskpack(const int* __restrict__ mask,
                                                  unsigned long long* __restrict__ mbits) {
  const int nwords = B_ * S_ * (S_ / 64);  // 524288
  const int wave = (blockIdx.x * 256 + threadIdx.x) >> 6;
  const int lane = threadIdx.x & 63;
  const int nwaves = gridDim.x * 4;
#pragma unroll 4
  for (int w = wave; w < nwords; w += nwaves) {
    int mk = mask[(size_t)w * 64 + lane];
    unsigned long long bal = __ballot(mk == 1);
    if (lane == 0) mbits[w] = bal;
  }
}

// ---------------- K1: projection GEMM  O = X @ W^T + b  (f32 in, bf16 out) -----------
__global__ __launch_bounds__(256) void k_proj(const float* __restrict__ qin,
                                              const float* __restrict__ kin,
                                              const float* __restrict__ vin,
                                              const float* __restrict__ W,
                                              const float* __restrict__ bias,
                                              unsigned short* __restrict__ qp,
                                              unsigned short* __restrict__ kp,
                                              unsigned short* __restrict__ vp) {
  __shared__ __attribute__((aligned(16))) unsigned short As[128 * 32];
  __shared__ __attribute__((aligned(16))) unsigned short Bs[128 * 32];
  const int tid = threadIdx.x;
  const int lane = tid & 63;
  const int wid = tid >> 6;
  const int wr = (wid >> 1) * 64;
  const int wc = (wid & 1) * 64;
  const int r0 = blockIdx.x * 128;
  const int c0 = blockIdx.y * 128;
  const int z = blockIdx.z;
  const float* X = (z == 0) ? qin : ((z == 1) ? kin : vin);
  unsigned short* O = (z == 0) ? qp : ((z == 1) ? kp : vp);

  f32x4 acc[4][4] = {};

  for (int k0 = 0; k0 < E_; k0 += 32) {
#pragma unroll
    for (int i = 0; i < 4; ++i) {
      int f = i * 256 + tid;
      int row = f >> 3, c4 = f & 7;
      float4 a = *reinterpret_cast<const float4*>(&X[(size_t)(r0 + row) * E_ + k0 + c4 * 4]);
      float4 w = *reinterpret_cast<const float4*>(&W[(size_t)(c0 + row) * E_ + k0 + c4 * 4]);
      uint2 pa, pw;
      pa.x = (unsigned)f2bf(a.x) | ((unsigned)f2bf(a.y) << 16);
      pa.y = (unsigned)f2bf(a.z) | ((unsigned)f2bf(a.w) << 16);
      pw.x = (unsigned)f2bf(w.x) | ((unsigned)f2bf(w.y) << 16);
      pw.y = (unsigned)f2bf(w.z) | ((unsigned)f2bf(w.w) << 16);
      *reinterpret_cast<uint2*>(&As[row * 32 + c4 * 4]) = pa;
      *reinterpret_cast<uint2*>(&Bs[row * 32 + c4 * 4]) = pw;
    }
    __syncthreads();
    bf16x8 af[4], bfr[4];
#pragma unroll
    for (int m = 0; m < 4; ++m)
      af[m] = *reinterpret_cast<const bf16x8*>(&As[(wr + m * 16 + (lane & 15)) * 32 + (lane >> 4) * 8]);
#pragma unroll
    for (int n = 0; n < 4; ++n)
      bfr[n] = *reinterpret_cast<const bf16x8*>(&Bs[(wc + n * 16 + (lane & 15)) * 32 + (lane >> 4) * 8]);
#pragma unroll
    for (int m = 0; m < 4; ++m)
#pragma unroll
      for (int n = 0; n < 4; ++n)
        acc[m][n] = __builtin_amdgcn_mfma_f32_16x16x32_bf16(af[m], bfr[n], acc[m][n], 0, 0, 0);
    __syncthreads();
  }

#pragma unroll
  for (int n = 0; n < 4; ++n) {
    int gc = c0 + wc + n * 16 + (lane & 15);
    float bv = bias[gc];
#pragma unroll
    for (int m = 0; m < 4; ++m) {
      int gr = r0 + wr + m * 16 + (lane >> 4) * 4;
#pragma unroll
      for (int r = 0; r < 4; ++r) {
        O[(size_t)(gr + r) * E_ + gc] = f2bf(acc[m][n][r] + bv);
      }
    }
  }
}

// ---------------- K1b: transpose vp [B*S][E] -> vpT [B][E][S] ------------------------
__global__ __launch_bounds__(256) void k_vtrans(const unsigned short* __restrict__ vp,
                                                unsigned short* __restrict__ vpT) {
  __shared__ __attribute__((aligned(16))) unsigned short t[64][72];
  const int tid = threadIdx.x;
  const int st = blockIdx.x;
  const int ot = blockIdx.y;
  const int b = blockIdx.z;
#pragma unroll
  for (int i = 0; i < 2; ++i) {
    int f = i * 256 + tid;
    int s = f >> 3, c8 = f & 7;
    uint4 vv = *reinterpret_cast<const uint4*>(
        &vp[((size_t)b * S_ + st * 64 + s) * E_ + ot * 64 + c8 * 8]);
    *reinterpret_cast<uint4*>(&t[s][c8 * 8]) = vv;
  }
  __syncthreads();
  const int o = tid >> 2;
  const int sb = (tid & 3) * 16;
  unsigned p[8];
#pragma unroll
  for (int j = 0; j < 8; ++j)
    p[j] = (unsigned)t[sb + 2 * j][o] | ((unsigned)t[sb + 2 * j + 1][o] << 16);
  uint4 w0 = make_uint4(p[0], p[1], p[2], p[3]);
  uint4 w1 = make_uint4(p[4], p[5], p[6], p[7]);
  size_t ob = ((size_t)b * E_ + ot * 64 + o) * S_ + st * 64 + sb;
  *reinterpret_cast<uint4*>(&vpT[ob]) = w0;
  *reinterpret_cast<uint4*>(&vpT[ob + 8]) = w1;
}

// ---------------- K2: scores tile GEMM + mask + exp (unnormalized) + rowsum ---------
__global__ __launch_bounds__(512, 2) void k_scores(const unsigned short* __restrict__ qp,
                                                   const unsigned short* __restrict__ kp,
                                                   const unsigned* __restrict__ mbits,
                                                   unsigned short* __restrict__ P,
                                                   float* __restrict__ rowsum) {
  __shared__ __attribute__((aligned(16))) unsigned short AsAll[3 * A_TILE_USH];  // 96 KB
  __shared__ __attribute__((aligned(16))) unsigned short BsAll[3 * B_TILE_USH];  // 48 KB
  __shared__ float rlds[256][2];
  const int tid = threadIdx.x, lane = tid & 63, wid = tid >> 6;
  const int wm = wid >> 1, wn = wid & 1;
  const int qt = blockIdx.x, yt = blockIdx.y, b = blockIdx.z;
  const char* Ab = (const char*)(qp + ((size_t)b * S_ + qt * 256) * E_);
  const char* Bb = (const char*)(kp + ((size_t)b * S_ + yt * 128) * E_);
  f32x4 acc[4][4] = {};
  gemm_pipe(Ab, Bb, E_ * 2, E_ * 2, E_ / 64, AsAll, BsAll, tid, wm, wn, lane, acc);

  const float SC = (float)(1.4426950408889634 / 27.712812921102035);  // log2(e)/sqrt(768)
  float rs[4][4];
#pragma unroll
  for (int m = 0; m < 4; ++m)
#pragma unroll
    for (int r = 0; r < 4; ++r) {
      const int grow = qt * 256 + wm * 64 + m * 16 + (lane >> 4) * 4 + r;
      const size_t rowoff = ((size_t)b * S_ + grow) * S_;
      const uint2 mb = *reinterpret_cast<const uint2*>(
          &mbits[((size_t)b * S_ + grow) * 64 + yt * 4 + wn * 2]);
      float radd = 0.f;
#pragma unroll
      for (int n = 0; n < 4; ++n) {
        const int gcol = yt * 128 + wn * 64 + n * 16 + (lane & 15);
        const unsigned wsel = (n & 2) ? mb.y : mb.x;
        const int sh = (lane & 15) + ((n & 1) << 4);
        float pv = ((wsel >> sh) & 1u) ? 0.f : __builtin_amdgcn_exp2f(acc[m][n][r] * SC);
        radd += pv;
        P[rowoff + gcol] = f2bf(pv);
      }
      rs[m][r] = radd;
    }

#pragma unroll
  for (int m = 0; m < 4; ++m)
#pragma unroll
    for (int r = 0; r < 4; ++r) {
      float vsum = rs[m][r];
      vsum += __shfl_xor(vsum, 1);
      vsum += __shfl_xor(vsum, 2);
      vsum += __shfl_xor(vsum, 4);
      vsum += __shfl_xor(vsum, 8);
      if ((lane & 15) == 0) rlds[wm * 64 + m * 16 + (lane >> 4) * 4 + r][wn] = vsum;
    }
  __syncthreads();
  if (tid < 256) {
    rowsum[(size_t)yt * (B_ * S_) + (size_t)b * S_ + qt * 256 + tid] =
        rlds[tid][0] + rlds[tid][1];
  }
}

// ---------------- K2b: inv_rs = 1 / sum_yt rowsum -----------------------------------
__global__ __launch_bounds__(256) void k_invrs(const float* __restrict__ rowsum,
                                               float* __restrict__ inv_rs) {
  int i = blockIdx.x * 256 + threadIdx.x;
  float t = 0.f;
#pragma unroll
  for (int g = 0; g < 16; ++g) t += rowsum[(size_t)g * (B_ * S_) + i];
  inv_rs[i] = 1.0f / t;
}

// ---------------- K3: out = (P @ vpT^T) * inv_rs  (f32 out) -------------------------
__global__ __launch_bounds__(512, 2) void k_pv(const unsigned short* __restrict__ P,
                                               const unsigned short* __restrict__ vpT,
                                               const float* __restrict__ inv_rs,
                                               float* __restrict__ out) {
  __shared__ __attribute__((aligned(16))) unsigned short AsAll[3 * A_TILE_USH];
  __shared__ __attribute__((aligned(16))) unsigned short BsAll[3 * B_TILE_USH];
  const int tid = threadIdx.x, lane = tid & 63, wid = tid >> 6;
  const int wm = wid >> 1, wn = wid & 1;
  const int mt = blockIdx.x, yt = blockIdx.y, b = blockIdx.z;
  const char* Ab = (const char*)(P + ((size_t)b * S_ + mt * 256) * S_);
  const char* Bb = (const char*)(vpT + ((size_t)b * E_ + yt * 128) * S_);
  f32x4 acc[4][4] = {};
  gemm_pipe(Ab, Bb, S_ * 2, S_ * 2, S_ / 64, AsAll, BsAll, tid, wm, wn, lane, acc);

#pragma unroll
  for (int m = 0; m < 4; ++m)
#pragma unroll
    for (int r = 0; r < 4; ++r) {
      const int grow = mt * 256 + wm * 64 + m * 16 + (lane >> 4) * 4 + r;
      const float inv = inv_rs[b * S_ + grow];
#pragma unroll
      for (int n = 0; n < 4; ++n) {
        const int gcol = yt * 128 + wn * 64 + n * 16 + (lane & 15);
        out[((size_t)b * S_ + grow) * E_ + gcol] = acc[m][n][r] * inv;
      }
    }
}

extern "C" void kernel_launch(void* const* d_in, const int* in_sizes, int n_in,
                              void* d_out, int out_size, void* d_ws, size_t ws_size,
                              hipStream_t stream) {
  const float* q = (const float*)d_in[0];
  const float* k = (const float*)d_in[1];
  const float* v = (const float*)d_in[2];
  const int* mask = (const int*)d_in[3];
  const float* W = (const float*)d_in[4];
  const float* bias = (const float*)d_in[5];
  float* out = (float*)d_out;
  char* ws = (char*)d_ws;

  // workspace layout (bytes)
  unsigned short* qp = (unsigned short*)(ws + 0);           //  24 MB
  unsigned short* kp = (unsigned short*)(ws + 25165824);    //  24 MB
  unsigned short* vpT = (unsigned short*)(ws + 50331648);   //  24 MB
  unsigned short* P = (unsigned short*)(ws + 75497472);     //  64 MiB
  unsigned short* vp_tmp = P;  // reused: consumed by k_vtrans before k_scores writes P
  float* rowsum = (float*)(ws + 142606336);                 // 16*B*S f32 = 1 MB
  float* inv_rs = (float*)(ws + 143654912);                 // B*S f32 = 64 KB
  unsigned long long* mbits = (unsigned long long*)(ws + 143720448);  // 4 MB
  (void)in_sizes; (void)n_in; (void)out_size; (void)ws_size;

  dim3 blk(256, 1, 1);
  dim3 blk2(512, 1, 1);
  k_maskpack<<<dim3(2048, 1, 1), blk, 0, stream>>>(mask, mbits);
  k_proj<<<dim3(128, 6, 3), blk, 0, stream>>>(q, k, v, W, bias, qp, kp, vp_tmp);
  k_vtrans<<<dim3(32, 12, 8), blk, 0, stream>>>(vp_tmp, vpT);
  k_scores<<<dim3(8, 16, 8), blk2, 0, stream>>>(qp, kp, (const unsigned*)mbits, P, rowsum);
  k_invrs<<<dim3(64, 1, 1), blk, 0, stream>>>(rowsum, inv_rs);
  k_pv<<<dim3(8, 6, 8), blk2, 0, stream>>>(P, vpT, inv_rs, out);
}